// Round 1
// baseline (81.574 us; speedup 1.0000x reference)
//
#include <hip/hip_runtime.h>
#include <math.h>

// QHashSoftmax: fixed-point LUT softmax.
//   idx = clamp(rint(x*16), -128, 127) & 255          (8-bit code)
//   e   = exp_tab[idx]            (integer, e*128 in [0,127])
//   S   = sum_row(e)              (integer, <= 130048)
//   n   = e==0 ? 1023 : min(S div e, 1023)
//   out = div_tab[n]              (f32)
// Per-row trick: output depends on element only via its 8-bit code, so build a
// 256-entry per-row output LUT after the reduction; per-element work = gathers.

#define ROW_LEN    1024
#define TOTAL_ROWS (4 * 12 * 1024)   // 49152
#define BLOCK      256
#define NBLOCKS    2048              // 24 rows per block, grid-stride

__global__ __launch_bounds__(1024) void build_tables_kernel(
        const float* __restrict__ scale_p,
        int*   __restrict__ exp_tab,
        float* __restrict__ div_tab)
{
    const int t = threadIdx.x;            // 0..1023
    const float scale = scale_p[0];
    if (t < 256) {
        const int s = (t >= 128) ? (t - 256) : t;        // two's-complement decode
        const float val = ((float)s * 0.0625f) * scale;  // (signed * 2^-4) * scale, f32 order matches JAX
        const float ex  = (float)exp((double)val);       // correctly-rounded f32 exp
        float q = rintf(ex * 128.0f);                    // round-half-even; *128 exact
        q = fminf(fmaxf(q, -128.0f), 127.0f);
        exp_tab[t] = (int)q;                             // in [0,127]
    }
    {
        const float inv = 1.0f / (float)t;               // t==0 -> +inf
        float q = rintf(inv * 128.0f);                   // inf stays inf
        q = fminf(fmaxf(q, -128.0f), 127.0f);            // inf -> 127 (matches jnp.clip)
        div_tab[t] = q * 0.0078125f;
    }
}

__global__ __launch_bounds__(BLOCK) void qhash_softmax_kernel(
        const float* __restrict__ x,
        const int*   __restrict__ exp_tab_g,
        const float* __restrict__ div_tab_g,
        float* __restrict__ out)
{
    __shared__ int   etab[256];
    __shared__ float dtab[1024];
    __shared__ float olut[256];            // per-row output LUT
    __shared__ int   wsum[BLOCK / 64];

    const int t = threadIdx.x;
    etab[t] = exp_tab_g[t];
    ((float4*)dtab)[t] = ((const float4*)div_tab_g)[t];
    __syncthreads();

    for (int row = blockIdx.x; row < TOTAL_ROWS; row += NBLOCKS) {
        const float4 xv = ((const float4*)(x + (size_t)row * ROW_LEN))[t];

        const int i0 = ((int)fminf(fmaxf(rintf(xv.x * 16.0f), -128.0f), 127.0f)) & 255;
        const int i1 = ((int)fminf(fmaxf(rintf(xv.y * 16.0f), -128.0f), 127.0f)) & 255;
        const int i2 = ((int)fminf(fmaxf(rintf(xv.z * 16.0f), -128.0f), 127.0f)) & 255;
        const int i3 = ((int)fminf(fmaxf(rintf(xv.w * 16.0f), -128.0f), 127.0f)) & 255;

        const int e0 = etab[i0];
        const int e1 = etab[i1];
        const int e2 = etab[i2];
        const int e3 = etab[i3];

        int local = e0 + e1 + e2 + e3;
        #pragma unroll
        for (int off = 32; off > 0; off >>= 1)
            local += __shfl_down(local, off);
        if ((t & 63) == 0) wsum[t >> 6] = local;
        __syncthreads();

        const int S = wsum[0] + wsum[1] + wsum[2] + wsum[3];

        // Build per-row output LUT: one f32 div per thread.
        // floor(RN(S/E)) == S div E exactly: |RN err| <= 2^-8 < 1/127 <= dist to
        // next integer (S <= 130048 < 2^24 exact; E in [1,127]).
        {
            const int e = etab[t];
            int n;
            if (e == 0) {
                n = 1023;
            } else {
                n = (int)floorf((float)S / (float)e);
                if (n > 1023) n = 1023;
            }
            olut[t] = dtab[n];
        }
        __syncthreads();

        float4 o;
        o.x = olut[i0];
        o.y = olut[i1];
        o.z = olut[i2];
        o.w = olut[i3];
        ((float4*)(out + (size_t)row * ROW_LEN))[t] = o;
        __syncthreads();   // protect wsum/olut before next row overwrites
    }
}

extern "C" void kernel_launch(void* const* d_in, const int* in_sizes, int n_in,
                              void* d_out, int out_size, void* d_ws, size_t ws_size,
                              hipStream_t stream) {
    const float* x       = (const float*)d_in[0];
    const float* scale_p = (const float*)d_in[1];
    float* out = (float*)d_out;

    int*   exp_tab = (int*)d_ws;                       // 256 * 4B
    float* div_tab = (float*)((char*)d_ws + 1024);     // 1024 * 4B, 16B-aligned

    build_tables_kernel<<<1, 1024, 0, stream>>>(scale_p, exp_tab, div_tab);
    qhash_softmax_kernel<<<NBLOCKS, BLOCK, 0, stream>>>(x, exp_tab, div_tab, out);
}

// Round 3
// 54.214 us; speedup vs baseline: 1.5047x; 1.5047x over previous
//
#include <hip/hip_runtime.h>
#include <math.h>

// QHashSoftmax: fixed-point LUT softmax.
//   idx = clamp(rint(x*16), -128, 127) & 255          (8-bit code)
//   e   = exp_tab[idx]            (integer, e*128 in [0,127])
//   S   = sum_row(e)              (integer, <= 130048)
//   n   = e==0 ? 1023 : min(S div e, 1023)
//   out = div_tab[n]
//
// R2 structure: one WAVE owns one row (64 lanes x 16 elem = 1024) -> no
// __syncthreads in the main loop (wave-synchronous per-wave olut in LDS;
// DS ops are in-order within a wave, lgkmcnt(0)+wave_barrier stop compiler
// reordering). Tables built per-block (kills the serialized setup dispatch).
// 1-row prefetch keeps 4x global_load_dwordx4 in flight under compute.
// floor(RN(S/E)) == S div E exactly: |RN err| <= 2^-8 < 1/127 (S < 2^18 exact).

#define ROW_LEN       1024
#define TOTAL_ROWS    (4 * 12 * 1024)          // 49152
#define BLOCK         256
#define NBLOCKS       2048
#define WPB           4                         // waves per block
#define TOTAL_WAVES   (NBLOCKS * WPB)           // 8192
#define ROWS_PER_WAVE (TOTAL_ROWS / TOTAL_WAVES) // 6, exact

typedef float floatx4 __attribute__((ext_vector_type(4)));  // native vec for nt-store

__device__ __forceinline__ int imin(int a, int b) { return a < b ? a : b; }

__global__ __launch_bounds__(BLOCK) void qhash_kernel(
        const float* __restrict__ x,
        const float* __restrict__ scale_p,
        float* __restrict__ out)
{
    __shared__ int   etab[256];
    __shared__ float dtab[1024];
    __shared__ float olut[WPB][256];

    const int t    = threadIdx.x;
    const int wave = t >> 6;
    const int lane = t & 63;

    // ---- per-block table build (parallel across all 2048 blocks) ----
    {
        const float scale = scale_p[0];
        const int   s   = (t >= 128) ? (t - 256) : t;     // two's-complement decode
        const float val = ((float)s * 0.0625f) * scale;   // matches JAX f32 order
        const float ex  = (float)exp((double)val);        // correctly-rounded f32 exp
        float q = rintf(ex * 128.0f);                     // round-half-even
        q = fminf(fmaxf(q, -128.0f), 127.0f);
        etab[t] = (int)q;                                 // in [0,127]
        #pragma unroll
        for (int k = 0; k < 4; ++k) {
            const int n = t + 256 * k;
            float d = rintf((1.0f / (float)n) * 128.0f);  // n==0 -> inf -> clamp 127
            d = fminf(fmaxf(d, -128.0f), 127.0f);
            dtab[n] = d * 0.0078125f;
        }
    }
    __syncthreads();   // only barrier in the kernel

    // e-values of the olut entries this lane owns
    const int ew0 = etab[lane];
    const int ew1 = etab[lane + 64];
    const int ew2 = etab[lane + 128];
    const int ew3 = etab[lane + 192];
    float* const ol = olut[wave];

    const int gw = blockIdx.x * WPB + wave;   // global wave id, 0..8191

    float4 cur[4];
    {
        const float4* p = (const float4*)(x + (size_t)gw * ROW_LEN);
        cur[0] = p[lane];       cur[1] = p[lane + 64];
        cur[2] = p[lane + 128]; cur[3] = p[lane + 192];
    }

    for (int it = 0; it < ROWS_PER_WAVE; ++it) {
        const int row = gw + it * TOTAL_WAVES;

        float4 nxt[4];
        if (it + 1 < ROWS_PER_WAVE) {
            const float4* p = (const float4*)(x + (size_t)(row + TOTAL_WAVES) * ROW_LEN);
            nxt[0] = p[lane];       nxt[1] = p[lane + 64];
            nxt[2] = p[lane + 128]; nxt[3] = p[lane + 192];
        }

        int idx[16];
        #pragma unroll
        for (int k = 0; k < 4; ++k) {
            const float4 v = cur[k];
            idx[4*k+0] = ((int)fminf(fmaxf(rintf(v.x * 16.0f), -128.0f), 127.0f)) & 255;
            idx[4*k+1] = ((int)fminf(fmaxf(rintf(v.y * 16.0f), -128.0f), 127.0f)) & 255;
            idx[4*k+2] = ((int)fminf(fmaxf(rintf(v.z * 16.0f), -128.0f), 127.0f)) & 255;
            idx[4*k+3] = ((int)fminf(fmaxf(rintf(v.w * 16.0f), -128.0f), 127.0f)) & 255;
        }

        int s = 0;
        #pragma unroll
        for (int j = 0; j < 16; ++j) s += etab[idx[j]];
        #pragma unroll
        for (int off = 1; off < 64; off <<= 1) s += __shfl_xor(s, off);
        // all 64 lanes now hold the row sum S

        const float fS = (float)s;
        ol[lane]       = dtab[(ew0 == 0) ? 1023 : imin((int)floorf(fS / (float)ew0), 1023)];
        ol[lane + 64]  = dtab[(ew1 == 0) ? 1023 : imin((int)floorf(fS / (float)ew1), 1023)];
        ol[lane + 128] = dtab[(ew2 == 0) ? 1023 : imin((int)floorf(fS / (float)ew2), 1023)];
        ol[lane + 192] = dtab[(ew3 == 0) ? 1023 : imin((int)floorf(fS / (float)ew3), 1023)];

        asm volatile("s_waitcnt lgkmcnt(0)" ::: "memory");  // wave-sync LDS: writes visible
        __builtin_amdgcn_wave_barrier();

        floatx4* const po = (floatx4*)(out + (size_t)row * ROW_LEN);
        #pragma unroll
        for (int k = 0; k < 4; ++k) {
            floatx4 o;
            o.x = ol[idx[4*k+0]];
            o.y = ol[idx[4*k+1]];
            o.z = ol[idx[4*k+2]];
            o.w = ol[idx[4*k+3]];
            __builtin_nontemporal_store(o, po + lane + 64 * k);
        }
        __builtin_amdgcn_wave_barrier();  // keep next-iter ol writes after these reads

        cur[0] = nxt[0]; cur[1] = nxt[1]; cur[2] = nxt[2]; cur[3] = nxt[3];
    }
}

extern "C" void kernel_launch(void* const* d_in, const int* in_sizes, int n_in,
                              void* d_out, int out_size, void* d_ws, size_t ws_size,
                              hipStream_t stream) {
    const float* x       = (const float*)d_in[0];
    const float* scale_p = (const float*)d_in[1];
    float* out = (float*)d_out;

    qhash_kernel<<<NBLOCKS, BLOCK, 0, stream>>>(x, scale_p, out);
}

// Round 4
// 53.842 us; speedup vs baseline: 1.5150x; 1.0069x over previous
//
#include <hip/hip_runtime.h>
#include <math.h>

// QHashSoftmax: fixed-point LUT softmax.
//   idx = clamp(rint(x*16), -128, 127) & 255          (8-bit code)
//   e   = exp_tab[idx]            (integer, e*128 in [0,127])
//   S   = sum_row(e)              (integer, <= 130048)
//   n   = e==0 ? 1023 : min(S div e, 1023)
//   out = div_tab[n]
//
// One WAVE owns one row (64 lanes x 16 elem = 1024); no __syncthreads in the
// main loop. R4: wave reduction via DPP (row_shr + row_bcast + readlane) on
// the VALU pipe instead of 6x ds_swizzle on the DS pipe -- cuts ~300 cyc of
// serial DS latency per row and ~295K DS instructions chip-wide.
// floor(RN(S/E)) == S div E exactly: |RN err| <= 2^-8 < 1/127 (S < 2^18 exact).

#define ROW_LEN       1024
#define TOTAL_ROWS    (4 * 12 * 1024)          // 49152
#define BLOCK         256
#define NBLOCKS       2048
#define WPB           4                         // waves per block
#define TOTAL_WAVES   (NBLOCKS * WPB)           // 8192
#define ROWS_PER_WAVE (TOTAL_ROWS / TOTAL_WAVES) // 6, exact

typedef float floatx4 __attribute__((ext_vector_type(4)));  // native vec for nt-store

__device__ __forceinline__ int imin(int a, int b) { return a < b ? a : b; }

// Canonical GCN full-wave integer sum: partial prefix within 16-lane rows,
// then row_bcast15 (rows 1,3) and row_bcast31 (rows 2,3); lane 63 holds the
// total. All lanes get it via readlane -> SGPR broadcast.
__device__ __forceinline__ int wave_reduce_sum(int v) {
    int t;
    t = __builtin_amdgcn_update_dpp(0, v, 0x111, 0xf, 0xf, true);  v += t; // row_shr:1
    t = __builtin_amdgcn_update_dpp(0, v, 0x112, 0xf, 0xf, true);  v += t; // row_shr:2
    t = __builtin_amdgcn_update_dpp(0, v, 0x114, 0xf, 0xf, true);  v += t; // row_shr:4
    t = __builtin_amdgcn_update_dpp(0, v, 0x118, 0xf, 0xf, true);  v += t; // row_shr:8
    t = __builtin_amdgcn_update_dpp(0, v, 0x142, 0xa, 0xf, false); v += t; // row_bcast:15
    t = __builtin_amdgcn_update_dpp(0, v, 0x143, 0xc, 0xf, false); v += t; // row_bcast:31
    return __builtin_amdgcn_readlane(v, 63);
}

__global__ __launch_bounds__(BLOCK) void qhash_kernel(
        const float* __restrict__ x,
        const float* __restrict__ scale_p,
        float* __restrict__ out)
{
    __shared__ int   etab[256];
    __shared__ float dtab[1024];
    __shared__ float olut[WPB][256];

    const int t    = threadIdx.x;
    const int wave = t >> 6;
    const int lane = t & 63;

    // ---- per-block table build (parallel across all 2048 blocks) ----
    {
        const float scale = scale_p[0];
        const int   s   = (t >= 128) ? (t - 256) : t;     // two's-complement decode
        const float val = ((float)s * 0.0625f) * scale;   // matches JAX f32 order
        const float ex  = (float)exp((double)val);        // correctly-rounded f32 exp
        float q = rintf(ex * 128.0f);                     // round-half-even
        q = fminf(fmaxf(q, -128.0f), 127.0f);
        etab[t] = (int)q;                                 // in [0,127]
        #pragma unroll
        for (int k = 0; k < 4; ++k) {
            const int n = t + 256 * k;
            float d = rintf((1.0f / (float)n) * 128.0f);  // n==0 -> inf -> clamp 127
            d = fminf(fmaxf(d, -128.0f), 127.0f);
            dtab[n] = d * 0.0078125f;
        }
    }
    __syncthreads();   // only barrier in the kernel

    // e-values of the olut entries this lane owns
    const int ew0 = etab[lane];
    const int ew1 = etab[lane + 64];
    const int ew2 = etab[lane + 128];
    const int ew3 = etab[lane + 192];
    float* const ol = olut[wave];

    const int gw = blockIdx.x * WPB + wave;   // global wave id, 0..8191

    float4 cur[4];
    {
        const float4* p = (const float4*)(x + (size_t)gw * ROW_LEN);
        cur[0] = p[lane];       cur[1] = p[lane + 64];
        cur[2] = p[lane + 128]; cur[3] = p[lane + 192];
    }

    for (int it = 0; it < ROWS_PER_WAVE; ++it) {
        const int row = gw + it * TOTAL_WAVES;

        float4 nxt[4];
        if (it + 1 < ROWS_PER_WAVE) {
            const float4* p = (const float4*)(x + (size_t)(row + TOTAL_WAVES) * ROW_LEN);
            nxt[0] = p[lane];       nxt[1] = p[lane + 64];
            nxt[2] = p[lane + 128]; nxt[3] = p[lane + 192];
        }

        int idx[16];
        #pragma unroll
        for (int k = 0; k < 4; ++k) {
            const float4 v = cur[k];
            idx[4*k+0] = ((int)fminf(fmaxf(rintf(v.x * 16.0f), -128.0f), 127.0f)) & 255;
            idx[4*k+1] = ((int)fminf(fmaxf(rintf(v.y * 16.0f), -128.0f), 127.0f)) & 255;
            idx[4*k+2] = ((int)fminf(fmaxf(rintf(v.z * 16.0f), -128.0f), 127.0f)) & 255;
            idx[4*k+3] = ((int)fminf(fmaxf(rintf(v.w * 16.0f), -128.0f), 127.0f)) & 255;
        }

        int s = 0;
        #pragma unroll
        for (int j = 0; j < 16; ++j) s += etab[idx[j]];
        const int S = wave_reduce_sum(s);          // uniform across the wave

        const float fS = (float)S;
        ol[lane]       = dtab[(ew0 == 0) ? 1023 : imin((int)floorf(fS / (float)ew0), 1023)];
        ol[lane + 64]  = dtab[(ew1 == 0) ? 1023 : imin((int)floorf(fS / (float)ew1), 1023)];
        ol[lane + 128] = dtab[(ew2 == 0) ? 1023 : imin((int)floorf(fS / (float)ew2), 1023)];
        ol[lane + 192] = dtab[(ew3 == 0) ? 1023 : imin((int)floorf(fS / (float)ew3), 1023)];

        asm volatile("s_waitcnt lgkmcnt(0)" ::: "memory");  // wave-sync LDS: writes visible
        __builtin_amdgcn_wave_barrier();

        floatx4* const po = (floatx4*)(out + (size_t)row * ROW_LEN);
        #pragma unroll
        for (int k = 0; k < 4; ++k) {
            floatx4 o;
            o.x = ol[idx[4*k+0]];
            o.y = ol[idx[4*k+1]];
            o.z = ol[idx[4*k+2]];
            o.w = ol[idx[4*k+3]];
            __builtin_nontemporal_store(o, po + lane + 64 * k);
        }
        __builtin_amdgcn_wave_barrier();  // keep next-iter ol writes after these reads

        cur[0] = nxt[0]; cur[1] = nxt[1]; cur[2] = nxt[2]; cur[3] = nxt[3];
    }
}

extern "C" void kernel_launch(void* const* d_in, const int* in_sizes, int n_in,
                              void* d_out, int out_size, void* d_ws, size_t ws_size,
                              hipStream_t stream) {
    const float* x       = (const float*)d_in[0];
    const float* scale_p = (const float*)d_in[1];
    float* out = (float*)d_out;

    qhash_kernel<<<NBLOCKS, BLOCK, 0, stream>>>(x, scale_p, out);
}